// Round 3
// baseline (339.958 us; speedup 1.0000x reference)
//
#include <hip/hip_runtime.h>
#include <hip/hip_bf16.h>
#include <stdint.h>

// Problem constants
#define BQ 128    // batch
#define NJ 512    // input capsules j
#define DD 300    // input dim
#define NC 10     // num_capsule i
#define DC 64     // dim_capsule k
#define MM 640    // NC*DC
#define KP 320    // K padded (mult of 64)
#define RT 5      // routing iterations

typedef __attribute__((ext_vector_type(8))) short short8;   // 8 bf16 = 4 VGPRs
typedef __attribute__((ext_vector_type(4))) float f32x4;

// ---------------- cast kernels ----------------

__global__ void k_cast_x(const float* __restrict__ x, __hip_bfloat16* __restrict__ xb) {
    int idx = blockIdx.x * 256 + threadIdx.x;          // 65536*320 total, exact grid
    int row = idx / KP, col = idx - row * KP;
    float v = (col < DD) ? x[(size_t)row * DD + col] : 0.f;
    xb[idx] = __float2bfloat16(v);
}

__global__ void k_cast_w(const float* __restrict__ w, __hip_bfloat16* __restrict__ wt) {
    int idx = blockIdx.x * 256 + threadIdx.x;          // 640*320 total, exact grid
    int m = idx / KP, k = idx - m * KP;
    float v = (k < DD) ? w[(size_t)k * MM + m] : 0.f;  // transpose: Wt[m][k] = W[k][m]
    wt[idx] = __float2bfloat16(v);
}

// ---------------- MFMA GEMM: u[65536][640] = xb[65536][320] * Wt^T ----------------
// 128x128 tile, BK=64 (32 MFMA per barrier pair), XOR-swizzled LDS (conflict-free
// frag reads), XCD-aware linear grid (all 5 n-tiles of an m-row on one XCD).

__global__ __launch_bounds__(256)
void k_gemm(const __hip_bfloat16* __restrict__ A,   // [65536][KP] row-major
            const __hip_bfloat16* __restrict__ Bt,  // [640][KP] row-major
            __hip_bfloat16* __restrict__ C) {       // [65536][640] row-major, bf16
    __shared__ __align__(16) __hip_bfloat16 As[128 * 64];
    __shared__ __align__(16) __hip_bfloat16 Bs[128 * 64];

    const int L  = blockIdx.x;                 // 2560 blocks
    const int n0 = ((L >> 3) % 5) * 128;       // same m-row's 5 n-tiles: same L%8 -> same XCD
    const int m0 = ((L / 40) * 8 + (L & 7)) * 128;
    const int t  = threadIdx.x;
    const int w  = t >> 6, lane = t & 63;
    const int wrow = (w >> 1) * 64, wcol = (w & 1) * 64;
    const int quad = lane >> 4, r = lane & 15;

    f32x4 acc[4][4] = {};

    // staging: issue s covers rows s*32 + (t>>3); thread loads 16 B.
    // source chunk XOR-swizzled so phys chunk (t&7) holds logical l^(row&7):
    const int srow = t >> 3;
    const int sl   = (t & 7) ^ (srow & 7);     // logical k-chunk this thread fetches
    const __hip_bfloat16* ag = A  + (size_t)(m0 + srow) * KP + sl * 8;
    const __hip_bfloat16* bg = Bt + (size_t)(n0 + srow) * KP + sl * 8;

    for (int kt = 0; kt < KP / 64; ++kt) {
        __syncthreads();
#pragma unroll
        for (int s = 0; s < 4; ++s) {
            __builtin_amdgcn_global_load_lds(
                (const __attribute__((address_space(1))) void*)(ag + (size_t)s * 32 * KP + kt * 64),
                (__attribute__((address_space(3))) void*)(&As[s * 2048 + t * 8]), 16, 0, 0);
            __builtin_amdgcn_global_load_lds(
                (const __attribute__((address_space(1))) void*)(bg + (size_t)s * 32 * KP + kt * 64),
                (__attribute__((address_space(3))) void*)(&Bs[s * 2048 + t * 8]), 16, 0, 0);
        }
        __syncthreads();

#pragma unroll
        for (int h = 0; h < 2; ++h) {          // two K=32 halves of the BK=64 tile
            short8 af[4], bf[4];
#pragma unroll
            for (int mi = 0; mi < 4; ++mi) {
                int rho = wrow + mi * 16 + r;
                int p = (h * 4 + quad) ^ (rho & 7);     // swizzled phys chunk
                af[mi] = *(const short8*)&As[rho * 64 + p * 8];
            }
#pragma unroll
            for (int ni = 0; ni < 4; ++ni) {
                int rho = wcol + ni * 16 + r;
                int p = (h * 4 + quad) ^ (rho & 7);
                bf[ni] = *(const short8*)&Bs[rho * 64 + p * 8];
            }
#pragma unroll
            for (int mi = 0; mi < 4; ++mi)
#pragma unroll
                for (int ni = 0; ni < 4; ++ni)
                    acc[mi][ni] = __builtin_amdgcn_mfma_f32_16x16x32_bf16(
                        af[mi], bf[ni], acc[mi][ni], 0, 0, 0);
        }
    }

    // epilogue: C/D layout col = lane&15, row = quad*4 + reg  [m89]
#pragma unroll
    for (int mi = 0; mi < 4; ++mi) {
#pragma unroll
        for (int ni = 0; ni < 4; ++ni) {
            int col = n0 + wcol + ni * 16 + r;
#pragma unroll
            for (int p = 0; p < 4; ++p) {
                int row = m0 + wrow + mi * 16 + quad * 4 + p;
                C[(size_t)row * MM + col] = __float2bfloat16(acc[mi][ni][p]);
            }
        }
    }
}

// ---------------- fused routing pass ----------------
// Block = (b, oct of j). 512 threads, 4 tiles of TJ=16 j (20480 B contiguous),
// register->LDS pipelined staging. jd = t>>5 (row in tile), kg = t&31 (k pair).
// bl reduced over kg via half-wave butterfly (kg == lane[4:0]); softmax per-lane.
// Barriers: 2 per tile.

#define TJ 16
#define NT 4
#define TILE_BYTES (TJ * MM * 2)   // 20480

__global__ __launch_bounds__(512)
void k_pass(const __hip_bfloat16* __restrict__ u, const float* __restrict__ osq,
            float* __restrict__ pbuf, int it) {
    // smem: ub 20480 (reused as reduce buf 20480) | outl 2560
    __shared__ __align__(16) char smem[TILE_BYTES + MM * 4];
    ushort* ub   = (ushort*)smem;                 // [16][640] bf16 tile
    float*  red  = (float*)smem;                  // reuse after last tile
    float*  outl = (float*)(smem + TILE_BYTES);   // [640] out_prev

    const int t   = threadIdx.x;
    const int blk = blockIdx.x;
    const int b   = blk >> 3, oct = blk & 7;
    const int w   = t >> 6;                       // wave
    const int jd  = t >> 5, kg = t & 31;

    if (it > 0 && t < 160)
        ((float4*)outl)[t] = ((const float4*)(osq + (size_t)b * MM))[t];

    const char* ubase = (const char*)(u + (size_t)(b * NJ + oct * 64) * MM);

    // preload tile 0
    uint4 sa = *(const uint4*)(ubase + t * 16);
    uint4 sb = *(const uint4*)(ubase + 8192 + t * 16);
    uint2 sc = *(const uint2*)(ubase + 16384 + t * 8);

    float po[20];
#pragma unroll
    for (int e = 0; e < 20; ++e) po[e] = 0.f;

    for (int tt = 0; tt < NT; ++tt) {
        uint4 na, nb; uint2 nc2;
        if (tt + 1 < NT) {                        // next tile's loads in flight
            const char* ns = ubase + (size_t)(tt + 1) * TILE_BYTES;
            na  = *(const uint4*)(ns + t * 16);
            nb  = *(const uint4*)(ns + 8192 + t * 16);
            nc2 = *(const uint2*)(ns + 16384 + t * 8);
        }
        __syncthreads();                          // prev tile compute done
        *(uint4*)((char*)ub + t * 16)        = sa;
        *(uint4*)((char*)ub + 8192 + t * 16) = sb;
        *(uint2*)((char*)ub + 16384 + t * 8) = sc;
        __syncthreads();                          // tile + outl visible

        const ushort* urow = ub + jd * MM;
        uint uv[10];
#pragma unroll
        for (int i = 0; i < 10; ++i)
            uv[i] = *(const uint*)(urow + i * 64 + kg * 2);   // bank=kg, 2-way free

        float c[10];
        if (it > 0) {
            float pbl[10];
#pragma unroll
            for (int i = 0; i < 10; ++i) {
                float u0 = __uint_as_float(uv[i] << 16);
                float u1 = __uint_as_float(uv[i] & 0xffff0000u);
                float2 oo = *(const float2*)(outl + i * 64 + kg * 2);
                pbl[i] = u0 * oo.x + u1 * oo.y;
            }
            // reduce over kg = lane[4:0]: butterfly stays within 32-lane half
#pragma unroll
            for (int i = 0; i < 10; ++i) {
#pragma unroll
                for (int m = 16; m >= 1; m >>= 1)
                    pbl[i] += __shfl_xor(pbl[i], m, 64);
            }
            float mx = -1e30f;
#pragma unroll
            for (int i = 0; i < 10; ++i) mx = fmaxf(mx, pbl[i]);
            float ssum = 0.f;
#pragma unroll
            for (int i = 0; i < 10; ++i) { pbl[i] = __expf(pbl[i] - mx); ssum += pbl[i]; }
            float inv = 1.f / ssum;
#pragma unroll
            for (int i = 0; i < 10; ++i) c[i] = pbl[i] * inv;
        } else {
#pragma unroll
            for (int i = 0; i < 10; ++i) c[i] = 0.1f;   // softmax of zeros
        }
#pragma unroll
        for (int i = 0; i < 10; ++i) {
            float u0 = __uint_as_float(uv[i] << 16);
            float u1 = __uint_as_float(uv[i] & 0xffff0000u);
            po[i * 2 + 0] += c[i] * u0;
            po[i * 2 + 1] += c[i] * u1;
        }
        sa = na; sb = nb; sc = nc2;
    }

    // reduce po over 16 jd: first fold the wave's two jd halves, then LDS over 8 waves
#pragma unroll
    for (int e = 0; e < 20; ++e) po[e] += __shfl_xor(po[e], 32, 64);
    __syncthreads();                              // ub dead -> reuse as red
    if ((t & 63) < 32) {
#pragma unroll
        for (int e = 0; e < 20; ++e) red[(w * 32 + kg) * 20 + e] = po[e];
    }
    __syncthreads();
    for (int m = t; m < MM; m += 512) {
        int i = m >> 6, k = m & 63, kg2 = k >> 1, kd = k & 1;
        float s = 0.f;
#pragma unroll
        for (int ww = 0; ww < 8; ++ww) s += red[(ww * 32 + kg2) * 20 + i * 2 + kd];
        pbuf[(size_t)blk * MM + m] = s;
    }
}

// squash: sum the 8 per-oct partials, normalize each (b,i) 64-vector
__global__ __launch_bounds__(640)
void k_squash(const float* __restrict__ pbuf, float* __restrict__ dst) {
    int b = blockIdx.x, t = threadIdx.x;     // t = i*64 + k; wave = i
    float s = 0.f;
#pragma unroll
    for (int qq = 0; qq < 8; ++qq) s += pbuf[(size_t)(b * 8 + qq) * MM + t];
    float sq = s * s;
#pragma unroll
    for (int m = 32; m >= 1; m >>= 1) sq += __shfl_xor(sq, m, 64);
    dst[(size_t)b * MM + t] = s * rsqrtf(sq + 1e-7f);
}

// ---------------- launch ----------------

extern "C" void kernel_launch(void* const* d_in, const int* in_sizes, int n_in,
                              void* d_out, int out_size, void* d_ws, size_t ws_size,
                              hipStream_t stream) {
    const float* x = (const float*)d_in[0];   // [128,512,300]
    const float* W = (const float*)d_in[1];   // [1,300,640]
    float* out = (float*)d_out;               // [128,10,64]

    char* ws = (char*)d_ws;
    size_t o = 0;
    __hip_bfloat16* xb = (__hip_bfloat16*)(ws + o); o += (size_t)BQ * NJ * KP * 2;  // 41.9 MB
    __hip_bfloat16* wt = (__hip_bfloat16*)(ws + o); o += (size_t)MM * KP * 2;       // 0.4 MB
    __hip_bfloat16* u  = (__hip_bfloat16*)(ws + o); o += (size_t)BQ * NJ * MM * 2;  // 83.9 MB
    float* pbuf = (float*)(ws + o); o += (size_t)1024 * MM * 4;                     // 2.6 MB
    float* osq  = (float*)(ws + o);                                                 // 0.33 MB

    k_cast_x<<<(BQ * NJ * KP) / 256, 256, 0, stream>>>(x, xb);
    k_cast_w<<<(MM * KP) / 256, 256, 0, stream>>>(W, wt);
    k_gemm<<<2560, 256, 0, stream>>>(xb, wt, u);

    for (int t = 0; t < RT; ++t) {
        k_pass<<<1024, 512, 0, stream>>>(u, osq, pbuf, t);
        k_squash<<<BQ, 640, 0, stream>>>(pbuf, (t == RT - 1) ? out : osq);
    }
}

// Round 4
// 256.146 us; speedup vs baseline: 1.3272x; 1.3272x over previous
//
#include <hip/hip_runtime.h>
#include <hip/hip_bf16.h>
#include <stdint.h>

// Problem constants
#define BQ 128    // batch
#define NJ 512    // input capsules j
#define DD 300    // input dim
#define NC 10     // num_capsule i
#define DC 64     // dim_capsule k
#define MM 640    // NC*DC
#define KP 320    // K padded (mult of 64)
#define RT 5      // routing iterations

typedef __attribute__((ext_vector_type(8))) short short8;   // 8 bf16 = 4 VGPRs
typedef __attribute__((ext_vector_type(4))) float f32x4;

// ---------------- cast kernels ----------------

// 8 elems/thread: 2x float4 load -> 8x cvt -> one 16 B store. Rows of x are
// 1200 B (16 B aligned), so every 8-col group is alignment-safe.
__global__ void k_cast_x(const float* __restrict__ x, __hip_bfloat16* __restrict__ xb) {
    int g = blockIdx.x * 256 + threadIdx.x;      // 65536*40 groups, exact grid
    int row = g / 40, cg = g - row * 40;
    const float* src = x + (size_t)row * DD + cg * 8;
    float4 a = make_float4(0.f, 0.f, 0.f, 0.f), b4 = a;
    if (cg < 37) { a = *(const float4*)src; b4 = *(const float4*)(src + 4); }
    else if (cg == 37) { a = *(const float4*)src; }   // cols 296-299; 300+ are pad
    union { ushort u[8]; uint4 v; } o;
    float f[8] = {a.x, a.y, a.z, a.w, b4.x, b4.y, b4.z, b4.w};
#pragma unroll
    for (int e = 0; e < 8; ++e) {
        __hip_bfloat16 h = __float2bfloat16(f[e]);
        o.u[e] = *(ushort*)&h;
    }
    *(uint4*)(xb + (size_t)row * KP + cg * 8) = o.v;
}

__global__ void k_cast_w(const float* __restrict__ w, __hip_bfloat16* __restrict__ wt) {
    int idx = blockIdx.x * 256 + threadIdx.x;          // 640*320 total, exact grid
    int m = idx / KP, k = idx - m * KP;
    float v = (k < DD) ? w[(size_t)k * MM + m] : 0.f;  // transpose: Wt[m][k] = W[k][m]
    wt[idx] = __float2bfloat16(v);
}

// ---------------- MFMA GEMM: u[65536][640] = xb[65536][320] * Wt^T ----------------
// 128x128 tile, BK=64, XOR-swizzled LDS, XCD-aware linear grid. (round-3 version)

__global__ __launch_bounds__(256)
void k_gemm(const __hip_bfloat16* __restrict__ A,   // [65536][KP] row-major
            const __hip_bfloat16* __restrict__ Bt,  // [640][KP] row-major
            __hip_bfloat16* __restrict__ C) {       // [65536][640] row-major, bf16
    __shared__ __align__(16) __hip_bfloat16 As[128 * 64];
    __shared__ __align__(16) __hip_bfloat16 Bs[128 * 64];

    const int L  = blockIdx.x;                 // 2560 blocks
    const int n0 = ((L >> 3) % 5) * 128;       // 5 n-tiles of an m-row share L%8 (same XCD)
    const int m0 = ((L / 40) * 8 + (L & 7)) * 128;
    const int t  = threadIdx.x;
    const int w  = t >> 6, lane = t & 63;
    const int wrow = (w >> 1) * 64, wcol = (w & 1) * 64;
    const int quad = lane >> 4, r = lane & 15;

    f32x4 acc[4][4] = {};

    const int srow = t >> 3;
    const int sl   = (t & 7) ^ (srow & 7);     // XOR-swizzled source chunk
    const __hip_bfloat16* ag = A  + (size_t)(m0 + srow) * KP + sl * 8;
    const __hip_bfloat16* bg = Bt + (size_t)(n0 + srow) * KP + sl * 8;

    for (int kt = 0; kt < KP / 64; ++kt) {
        __syncthreads();
#pragma unroll
        for (int s = 0; s < 4; ++s) {
            __builtin_amdgcn_global_load_lds(
                (const __attribute__((address_space(1))) void*)(ag + (size_t)s * 32 * KP + kt * 64),
                (__attribute__((address_space(3))) void*)(&As[s * 2048 + t * 8]), 16, 0, 0);
            __builtin_amdgcn_global_load_lds(
                (const __attribute__((address_space(1))) void*)(bg + (size_t)s * 32 * KP + kt * 64),
                (__attribute__((address_space(3))) void*)(&Bs[s * 2048 + t * 8]), 16, 0, 0);
        }
        __syncthreads();

#pragma unroll
        for (int h = 0; h < 2; ++h) {
            short8 af[4], bf[4];
#pragma unroll
            for (int mi = 0; mi < 4; ++mi) {
                int rho = wrow + mi * 16 + r;
                int p = (h * 4 + quad) ^ (rho & 7);
                af[mi] = *(const short8*)&As[rho * 64 + p * 8];
            }
#pragma unroll
            for (int ni = 0; ni < 4; ++ni) {
                int rho = wcol + ni * 16 + r;
                int p = (h * 4 + quad) ^ (rho & 7);
                bf[ni] = *(const short8*)&Bs[rho * 64 + p * 8];
            }
#pragma unroll
            for (int mi = 0; mi < 4; ++mi)
#pragma unroll
                for (int ni = 0; ni < 4; ++ni)
                    acc[mi][ni] = __builtin_amdgcn_mfma_f32_16x16x32_bf16(
                        af[mi], bf[ni], acc[mi][ni], 0, 0, 0);
        }
    }

#pragma unroll
    for (int mi = 0; mi < 4; ++mi) {
#pragma unroll
        for (int ni = 0; ni < 4; ++ni) {
            int col = n0 + wcol + ni * 16 + r;
#pragma unroll
            for (int p = 0; p < 4; ++p) {
                int row = m0 + wrow + mi * 16 + quad * 4 + p;
                C[(size_t)row * MM + col] = __float2bfloat16(acc[mi][ni][p]);
            }
        }
    }
}

// ---------------- fused routing pass (squash of prev iter fused in) ----------------
// Block = (b, quarter q). 512 threads, 8 tiles of TJ=16 j, register->LDS pipelined
// staging. Prologue: recompute osq from prev pass's pbuf partials (ping-pong).
// bl reduce: LDS transpose (write 10 partials, 160 threads serial-sum 32) — the
// round-2 scheme; op-optimal vs butterfly (ds_swizzle = LDS pipe, 4x traffic).

#define TJ 16
#define NT 8
#define TILE_BYTES (TJ * MM * 2)   // 20480

__global__ __launch_bounds__(512)
void k_pass(const __hip_bfloat16* __restrict__ u, const float* __restrict__ pprev,
            float* __restrict__ pnext, int it) {
    // smem: ub 20480 | red 32*161*4=20608 | blj 640 | outl 2560   (44288 B)
    __shared__ __align__(16) char smem[TILE_BYTES + 32 * 161 * 4 + 160 * 4 + MM * 4];
    ushort* ub    = (ushort*)smem;                          // [16][640] bf16 tile
    float*  red   = (float*)(smem + TILE_BYTES);            // [32][161] padded
    float*  blj   = (float*)(smem + TILE_BYTES + 20608);    // [160] = [jd][i]
    float*  outl  = (float*)(smem + TILE_BYTES + 20608 + 640); // [640] out_prev
    float*  pored = (float*)smem;                           // epilogue reuse (20480 B)

    const int t   = threadIdx.x;
    const int blk = blockIdx.x;
    const int b   = blk >> 2, q = blk & 3;
    const int w   = t >> 6, lane = t & 63;
    const int jd  = t >> 5, kg = t & 31;

    const char* ubase = (const char*)(u + (size_t)(b * NJ + q * 128) * MM);

    // preload tile 0 (in flight during prologue)
    uint4 sa = *(const uint4*)(ubase + t * 16);
    uint4 sb = *(const uint4*)(ubase + 8192 + t * 16);
    uint2 sc = *(const uint2*)(ubase + 16384 + t * 8);

    // prologue: osq = squash(sum of 4 pbuf chunks) — waves 0..4, two i each
    if (it > 0 && w < 5) {
        const float* pp = pprev + (size_t)b * 4 * MM;
        float s0 = 0.f, s1 = 0.f;
#pragma unroll
        for (int qq = 0; qq < 4; ++qq) {
            s0 += pp[qq * MM + w * 64 + lane];
            s1 += pp[qq * MM + 320 + w * 64 + lane];
        }
        float q0 = s0 * s0, q1 = s1 * s1;
#pragma unroll
        for (int m = 32; m >= 1; m >>= 1) {
            q0 += __shfl_xor(q0, m, 64);
            q1 += __shfl_xor(q1, m, 64);
        }
        outl[w * 64 + lane]       = s0 * rsqrtf(q0 + 1e-7f);
        outl[320 + w * 64 + lane] = s1 * rsqrtf(q1 + 1e-7f);
    }

    float po[20];
#pragma unroll
    for (int e = 0; e < 20; ++e) po[e] = 0.f;

    for (int tt = 0; tt < NT; ++tt) {
        uint4 na, nb; uint2 nc2;
        if (tt + 1 < NT) {                        // next tile's loads in flight
            const char* ns = ubase + (size_t)(tt + 1) * TILE_BYTES;
            na  = *(const uint4*)(ns + t * 16);
            nb  = *(const uint4*)(ns + 8192 + t * 16);
            nc2 = *(const uint2*)(ns + 16384 + t * 8);
        }
        __syncthreads();                          // prev tile compute done (also: outl visible)
        *(uint4*)((char*)ub + t * 16)        = sa;
        *(uint4*)((char*)ub + 8192 + t * 16) = sb;
        *(uint2*)((char*)ub + 16384 + t * 8) = sc;
        __syncthreads();                          // tile visible

        const ushort* urow = ub + jd * MM;
        uint uv[10];
#pragma unroll
        for (int i = 0; i < 10; ++i)
            uv[i] = *(const uint*)(urow + i * 64 + kg * 2);   // 2-way bank alias, free

        float c[10];
        if (it > 0) {
#pragma unroll
            for (int i = 0; i < 10; ++i) {
                float u0 = __uint_as_float(uv[i] << 16);
                float u1 = __uint_as_float(uv[i] & 0xffff0000u);
                float2 oo = *(const float2*)(outl + i * 64 + kg * 2);
                red[kg * 161 + jd * 10 + i] = u0 * oo.x + u1 * oo.y;
            }
            __syncthreads();
            if (t < 160) {                        // t = jd*10 + i
                float s = 0.f;
#pragma unroll
                for (int g = 0; g < 32; ++g) s += red[g * 161 + t];
                blj[t] = s;
            }
            __syncthreads();
            float bl[10], mx = -1e30f;
#pragma unroll
            for (int i = 0; i < 10; ++i) { bl[i] = blj[jd * 10 + i]; mx = fmaxf(mx, bl[i]); }
            float ssum = 0.f;
#pragma unroll
            for (int i = 0; i < 10; ++i) { bl[i] = __expf(bl[i] - mx); ssum += bl[i]; }
            float inv = 1.f / ssum;
#pragma unroll
            for (int i = 0; i < 10; ++i) c[i] = bl[i] * inv;
        } else {
#pragma unroll
            for (int i = 0; i < 10; ++i) c[i] = 0.1f;   // softmax of zeros
        }
#pragma unroll
        for (int i = 0; i < 10; ++i) {
            float u0 = __uint_as_float(uv[i] << 16);
            float u1 = __uint_as_float(uv[i] & 0xffff0000u);
            po[i * 2 + 0] += c[i] * u0;
            po[i * 2 + 1] += c[i] * u1;
        }
        sa = na; sb = nb; sc = nc2;
    }

    // epilogue: fold jd-halves in-register, then LDS transpose over 8 waves
#pragma unroll
    for (int e = 0; e < 20; ++e) po[e] += __shfl_xor(po[e], 32, 64);
    __syncthreads();                              // ub dead -> reuse as pored
    if ((t & 63) < 32) {
#pragma unroll
        for (int e = 0; e < 20; ++e) pored[(w * 32 + kg) * 20 + e] = po[e];
    }
    __syncthreads();
    for (int m = t; m < MM; m += 512) {
        int i = m >> 6, k = m & 63, kg2 = k >> 1, kd = k & 1;
        float s = 0.f;
#pragma unroll
        for (int ww = 0; ww < 8; ++ww) s += pored[(ww * 32 + kg2) * 20 + i * 2 + kd];
        pnext[(size_t)blk * MM + m] = s;
    }
}

// final squash: sum the 4 per-quarter partials, normalize each (b,i) 64-vector
__global__ __launch_bounds__(640)
void k_squash(const float* __restrict__ pbuf, float* __restrict__ dst) {
    int b = blockIdx.x, t = threadIdx.x;     // t = i*64 + k; wave = i
    float s = 0.f;
#pragma unroll
    for (int qq = 0; qq < 4; ++qq) s += pbuf[(size_t)(b * 4 + qq) * MM + t];
    float sq = s * s;
#pragma unroll
    for (int m = 32; m >= 1; m >>= 1) sq += __shfl_xor(sq, m, 64);
    dst[(size_t)b * MM + t] = s * rsqrtf(sq + 1e-7f);
}

// ---------------- launch ----------------

extern "C" void kernel_launch(void* const* d_in, const int* in_sizes, int n_in,
                              void* d_out, int out_size, void* d_ws, size_t ws_size,
                              hipStream_t stream) {
    const float* x = (const float*)d_in[0];   // [128,512,300]
    const float* W = (const float*)d_in[1];   // [1,300,640]
    float* out = (float*)d_out;               // [128,10,64]

    char* ws = (char*)d_ws;
    size_t o = 0;
    __hip_bfloat16* xb = (__hip_bfloat16*)(ws + o); o += (size_t)BQ * NJ * KP * 2;  // 41.9 MB
    __hip_bfloat16* wt = (__hip_bfloat16*)(ws + o); o += (size_t)MM * KP * 2;       // 0.4 MB
    __hip_bfloat16* u  = (__hip_bfloat16*)(ws + o); o += (size_t)BQ * NJ * MM * 2;  // 83.9 MB
    float* pb0 = (float*)(ws + o); o += (size_t)512 * MM * 4;                       // 1.3 MB
    float* pb1 = (float*)(ws + o); o += (size_t)512 * MM * 4;                       // 1.3 MB

    k_cast_x<<<(BQ * NJ * 40) / 256, 256, 0, stream>>>(x, xb);
    k_cast_w<<<(MM * KP) / 256, 256, 0, stream>>>(W, wt);
    k_gemm<<<2560, 256, 0, stream>>>(xb, wt, u);

    float* pb[2] = {pb0, pb1};
    for (int t = 0; t < RT; ++t)
        k_pass<<<512, 512, 0, stream>>>(u, pb[(t + 1) & 1], pb[t & 1], t);
    k_squash<<<BQ, 640, 0, stream>>>(pb[(RT - 1) & 1], out);
}